// Round 38
// baseline (60.385 us; speedup 1.0000x reference)
//
#include <hip/hip_runtime.h>
#include <utility>

#define D_DIM 256
#define WID   33
#define CEN   16
#define RITER 16                 // output rows per iteration
#define NI    16                 // iterations per block
#define CHUNK (RITER * NI)       // 256 output rows per block
#define RING  64                 // ring slots (fp32 rows, identity mapping)
#define PROL  48                 // prologue staged rows
#define GSTR  2080               // dwords per 8-slot group (2048 + 32 pad)
#define ASTRD 40                 // dwords per A row (80 u16 = 64 k + pad)

// R37 (60.2us) + ONE fix: slot-group bank swizzle. R37's 4.6M conflicts:
// quarter-groups differ by slot 8 -> 8*256 dwords = 0 mod 32 banks ->
// 4-way on every b32 frag read. New layout: addr(s) = (s>>3)*2080 +
// (s&7)*256 + ((s>>3)&3)*8. Since q8 = 0 mod 8 and KS*32 = 0 mod 8, frag
// reads stay compile-time off per-lane base h*2088 + wv*64 + l15; banks =
// l15 + 8h -> 2-way worst (free, m136). DMA dest wave-uniform + 16B-
// aligned; 32-dword group pad kills cross-group overlap. Else R37-exact.

typedef float  f32x4  __attribute__((ext_vector_type(4)));
typedef __bf16 bf16x8 __attribute__((ext_vector_type(8)));

__device__ __forceinline__ int clampN(int p, int N) {
    return p < 0 ? 0 : (p >= N ? N - 1 : p);
}

__device__ __forceinline__ int slotAddr(int s) {      // dword offset of slot s
    return (s >> 3) * GSTR + (s & 7) * 256 + ((s >> 3) & 3) * 8;
}

__device__ __forceinline__ unsigned short bfb(float f) {
    __bf16 b = (__bf16)f;
    return __builtin_bit_cast(unsigned short, b);
}

__device__ __forceinline__ unsigned packbf(float lo, float hi) {
    return (unsigned)bfb(lo) | ((unsigned)bfb(hi) << 16);
}

__device__ __forceinline__ bf16x8 ldfragd(const unsigned* dw) {
    const uint4 v = *reinterpret_cast<const uint4*>(dw);
    return __builtin_bit_cast(bf16x8, v);
}

__device__ __forceinline__ void dma_row(float* xs, int slot,
                                        const float* __restrict__ xlane,
                                        int row) {
    __builtin_amdgcn_global_load_lds(
        (const __attribute__((address_space(1))) void*)(xlane +
                                                        (size_t)row * D_DIM),
        (__attribute__((address_space(3))) void*)(xs + slotAddr(slot)), 16, 0, 0);
}

template <size_t... Ss>
__device__ __forceinline__ void stage_prol(float* xs,
                                           const float* __restrict__ xlane,
                                           int base0, int N, int wv,
                                           std::index_sequence<Ss...>) {
    (([&] {
         const int s = wv * (PROL / 4) + (int)Ss;      // 12 rows per wave
         dma_row(xs, s, xlane, clampN(base0 + s, N));
     }()),
     ...);
}

// stage 16 rows (4 per wave): row n0+32+16m+k -> slot (48+16m+k) & 63
__device__ __forceinline__ void stage_iter(float* xs,
                                           const float* __restrict__ xlane,
                                           int base0, int m, int N, int wv) {
#pragma unroll
    for (int kk = 0; kk < 4; ++kk) {
        const int k = wv * 4 + kk;
        const int s = (PROL + RITER * m + k) & (RING - 1);
        dma_row(xs, s, xlane, clampN(base0 + PROL + RITER * m + k, N));
    }
}

// ---- A staging: pre-rotated banded weights for target iter mt ----
template <size_t... Js>
__device__ __forceinline__ void loadA(float (&wf)[4],
                                      const float* __restrict__ smb,
                                      int R0, int g, int k0, int mt,
                                      std::index_sequence<Js...>) {
    (([&] {
         const int kw  = (k0 + (int)Js - RITER * mt) & (RING - 1);
         int tap = kw - g;
         tap = tap < 0 ? 0 : (tap > 32 ? 32 : tap);
         wf[Js] = smb[(size_t)(R0 + g) * WID + tap];   // R0+g < N always
     }()),
     ...);
}

__device__ __forceinline__ void writeA(unsigned* AlB, const float (&wf)[4],
                                       int R0, int g, int k0, int mt, int N) {
    float v[4];
#pragma unroll
    for (int j = 0; j < 4; ++j) {
        const int kw  = (k0 + j - RITER * mt) & (RING - 1);
        const int tap = kw - g;
        const int xr  = R0 - CEN + kw;
        v[j] = ((unsigned)tap < (unsigned)WID && (unsigned)xr < (unsigned)N)
                   ? wf[j] : 0.0f;
    }
    uint2 aw;
    aw.x = packbf(v[0], v[1]);
    aw.y = packbf(v[2], v[3]);
    *(uint2*)(AlB + g * ASTRD + (k0 >> 1)) = aw;
}

template <size_t... Js>
__device__ __forceinline__ void loadSZ(float (&sz)[4],
                                       const float* __restrict__ szb,
                                       int R, int q4, int N,
                                       std::index_sequence<Js...>) {
    ((sz[Js] = szb[clampN(R + q4 + (int)Js, N)]), ...);
}

// ---- B fragment: 8 fp32 ring reads (compile-time offsets) + cvt ----
// lane base xsb = xs + h*(GSTR+8) + wv*64 + l15; slot s=q8+KS*32+j lives at
// (h+4KS)*GSTR + j*256 + h*8 -> read offset = 4*KS*GSTR + j*256.
template <int KS, int IS>
__device__ __forceinline__ bf16x8 bfrag(const float* xsb) {
    uint4 r;
    r.x = packbf(xsb[4 * KS * GSTR + 0 * 256 + IS * 16],
                 xsb[4 * KS * GSTR + 1 * 256 + IS * 16]);
    r.y = packbf(xsb[4 * KS * GSTR + 2 * 256 + IS * 16],
                 xsb[4 * KS * GSTR + 3 * 256 + IS * 16]);
    r.z = packbf(xsb[4 * KS * GSTR + 4 * 256 + IS * 16],
                 xsb[4 * KS * GSTR + 5 * 256 + IS * 16]);
    r.w = packbf(xsb[4 * KS * GSTR + 6 * 256 + IS * 16],
                 xsb[4 * KS * GSTR + 7 * 256 + IS * 16]);
    return __builtin_bit_cast(bf16x8, r);
}

template <size_t... Is>
__device__ __forceinline__ void compute(f32x4 (&acc)[4], const float* xsb,
                                        const unsigned* AlB, int g, int q8,
                                        std::index_sequence<Is...>) {
    const bf16x8 af0 = ldfragd(AlB + g * ASTRD + (q8 >> 1));
    const bf16x8 af1 = ldfragd(AlB + g * ASTRD + (q8 >> 1) + 16);
    (([&] {
         const bf16x8 b0 = bfrag<0, (int)Is>(xsb);
         const bf16x8 b1 = bfrag<1, (int)Is>(xsb);
         acc[Is] = __builtin_amdgcn_mfma_f32_16x16x32_bf16(af0, b0, acc[Is], 0, 0, 0);
         acc[Is] = __builtin_amdgcn_mfma_f32_16x16x32_bf16(af1, b1, acc[Is], 0, 0, 0);
     }()),
     ...);
}

// ---- epilogue: scale + plain stores (C: col=lane&15, row=(l>>4)*4+reg) ----
template <size_t... Ts>
__device__ __forceinline__ void epi(const f32x4 (&acc)[4], const float (&sz)[4],
                                    float* __restrict__ obase, int R0m,
                                    std::index_sequence<Ts...>) {
    float inv[4];
#pragma unroll
    for (int j = 0; j < 4; ++j)
        inv[j] = __builtin_amdgcn_rcpf(fmaxf(sz[j], 1e-6f));
    (([&] {
         constexpr int i = (int)Ts / 4, j = (int)Ts % 4;
         obase[(size_t)(R0m + j) * D_DIM + i * 16] = acc[i][j] * inv[j];
     }()),
     ...);
}

__global__ __launch_bounds__(256) void local_enc_kernel(
    const float* __restrict__ x, const float* __restrict__ sizev,
    const float* __restrict__ sm, float* __restrict__ out, int N) {
    __shared__ float xs[8 * GSTR];           // 65 KB swizzled fp32 ring
    __shared__ unsigned Al[2][16 * ASTRD];   // 2 x 2.5 KB pre-rotated A

    // XCD swizzle: XCD k owns batch k, strips consecutive -> L2-local
    const int bid   = blockIdx.x;
    const int swz   = (bid & 7) * 64 + (bid >> 3);
    const int strip = swz & 63;
    const int b     = swz >> 6;
    const int n0    = strip * CHUNK;
    const int tid   = threadIdx.x;
    const int wv    = tid >> 6;
    const int lane  = tid & 63;

    const size_t bN = (size_t)b * (size_t)N;
    const float* __restrict__ xlane = x + bN * D_DIM + lane * 4;
    const float* __restrict__ smb   = sm + bN * WID;
    const float* __restrict__ szb   = sizev + bN;

    const int g  = tid & 15;          // A staging: output row
    const int k0 = (tid >> 4) * 4;    // A staging: kappa base (0..60)
    const int h  = lane >> 4;         // quarter-group
    const int q8 = h * 8;             // fragment k-group
    const int q4 = h * 4;             // epilogue row quarter

    const float* xsb = xs + h * (GSTR + 8) + wv * 64 + (lane & 15);
    float* __restrict__ obase =
        out + (bN + (size_t)q4) * D_DIM + wv * 64 + (lane & 15);

    // ---- prologue ----
    stage_prol(xs, xlane, n0 - CEN, N, wv, std::make_index_sequence<PROL / 4>{});
#pragma unroll
    for (int i = 0; i < 17; ++i) {           // zero groups 6,7 (slots 48..63)
        const int idx = 6 * GSTR + i * 256 + tid;
        if (idx < 8 * GSTR) xs[idx] = 0.0f;
    }

    float wf0[4];
    loadA(wf0, smb, n0, g, k0, 0, std::make_index_sequence<4>{});
    writeA(Al[0], wf0, n0, g, k0, 0, N);

    float szc[4];
    loadSZ(szc, szb, n0, q4, N, std::make_index_sequence<4>{});
    __syncthreads();

    // ---- main loop ----
#pragma unroll 1
    for (int m = 0; m < NI; ++m) {
        const int R0m = n0 + RITER * m;
        const bool more = (m < NI - 1);

        // phase 1: issue next-tile DMA first (vmcnt accounting), then
        // next-iter A/size loads (land under compute)
        float wfn[4];
        float szn[4];
        if (more) {
            stage_iter(xs, xlane, n0 - CEN, m, N, wv);
            loadA(wfn, smb, R0m + RITER, g, k0, m + 1,
                  std::make_index_sequence<4>{});
            loadSZ(szn, szb, R0m + RITER, q4, N, std::make_index_sequence<4>{});
        }
        __builtin_amdgcn_sched_barrier(0);

        // phase 2: MFMA compute from the ring (identity slots + swizzle)
        f32x4 acc[4] = {};
        compute(acc, xsb, Al[m & 1], g, q8, std::make_index_sequence<4>{});
        epi(acc, szc, obase, R0m, std::make_index_sequence<16>{});

        // phase 3: write next iter's A tile (other buffer) + sz handoff
        if (more) {
            writeA(Al[(m + 1) & 1], wfn, R0m + RITER, g, k0, m + 1, N);
#pragma unroll
            for (int j = 0; j < 4; ++j) szc[j] = szn[j];
        }

        // counted barrier: 4 A + 1 sz loads + 16 stores younger than the
        // 4 DMAs -> vmcnt(21); lgkmcnt(0) publishes writeA before barrier.
        __builtin_amdgcn_sched_barrier(0);
        asm volatile("s_waitcnt vmcnt(21) lgkmcnt(0)" ::: "memory");
        __builtin_amdgcn_s_barrier();
        __builtin_amdgcn_sched_barrier(0);
    }
}

extern "C" void kernel_launch(void* const* d_in, const int* in_sizes, int n_in,
                              void* d_out, int out_size, void* d_ws, size_t ws_size,
                              hipStream_t stream) {
    const float* x  = (const float*)d_in[0];
    const float* sz = (const float*)d_in[1];
    const float* sm = (const float*)d_in[2];
    float* out = (float*)d_out;

    const int B = 8;
    const int N = 16384;

    dim3 grid((N / CHUNK) * B, 1, 1);   // 64 x 8 = 512 blocks, XCD-swizzled
    dim3 block(256, 1, 1);
    local_enc_kernel<<<grid, block, 0, stream>>>(x, sz, sm, out, N);
}

// Round 39
// 55.219 us; speedup vs baseline: 1.0935x; 1.0935x over previous
//
#include <hip/hip_runtime.h>
#include <utility>

#define D_DIM 256
#define WID   33
#define CEN   16
#define RACC  4                    // output rows per thread (per wave-group)
#define XROWS (RACC + 2 * CEN)     // 36 x-rows read per thread per iter
#define RITER 16                   // output rows per iteration (4 waves x 4)
#define NI    16                   // iterations per block
#define CHUNK (RITER * NI)         // 256 output rows per block
#define RING  64                   // ring rows = 64 KB LDS (2 blocks/CU)
#define PROL  48                   // prologue staged rows (= RITER + 32)

// CHAMPION RESTORE (R34, 54.4us). R35-R38 MFMA arm: 60-70us, conflicts
// proven structural (R38: bank swizzle left the 4.59M count bit-identical
// -> source is DMA LDS-writes/writeA, layout-invariant). 38-round record:
// every structure family brackets a 54-60us co-binding plateau (HBM ~55%,
// LDS ~40%, VALU ~26%, occupancy pinned by RING >= 2*RITER+32 at fp32).
// Components, each counter-verified: fp32 DMA ring (R21: +latency-free
// staging), f32x4 scatter + readlane weights (R28), NT stores (R32:
// write-path relief), counted vmcnt(9) barrier (R34: NT-ack bypass).

typedef float f32x4 __attribute__((ext_vector_type(4)));

__device__ __forceinline__ float rdlane(float v, int l) {
    return __uint_as_float(__builtin_amdgcn_readlane(__float_as_uint(v), l));
}

__device__ __forceinline__ int clampN(int p, int N) {
    return p < 0 ? 0 : (p >= N ? N - 1 : p);
}

__device__ __forceinline__ f32x4 ld4(const float* p) {
    return *(const f32x4*)p;
}

__device__ __forceinline__ void dma_row(float* xs, int slot,
                                        const float* __restrict__ xlane,
                                        int row) {
    __builtin_amdgcn_global_load_lds(
        (const __attribute__((address_space(1))) void*)(xlane +
                                                        (size_t)row * D_DIM),
        (__attribute__((address_space(3))) void*)(xs + slot * D_DIM), 16, 0, 0);
}

template <size_t... Ss>
__device__ __forceinline__ void stage_prol(float* xs,
                                           const float* __restrict__ xlane,
                                           int base0, int N, int wv,
                                           std::index_sequence<Ss...>) {
    (([&] {
         const int s = wv * (PROL / 4) + (int)Ss;      // 12 rows per wave
         dma_row(xs, s, xlane, clampN(base0 + s, N));
     }()),
     ...);
}

// stage 16 rows (4 per wave): row n0+32+16m+k -> slot (48+16m+k) & 63
__device__ __forceinline__ void stage_iter(float* xs,
                                           const float* __restrict__ xlane,
                                           int base0, int m, int N, int wv) {
#pragma unroll
    for (int kk = 0; kk < 4; ++kk) {
        const int k = wv * 4 + kk;
        const int s = (PROL + RITER * m + k) & (RING - 1);
        dma_row(xs, s, xlane, clampN(base0 + PROL + RITER * m + k, N));
    }
}

template <size_t... Rs>
__device__ __forceinline__ void load_w(float (&w)[RACC],
                                       const float* __restrict__ smb,
                                       int nbase, int minl, int N,
                                       std::index_sequence<Rs...>) {
    ((w[Rs] = smb[(size_t)clampN(nbase + (int)Rs, N) * WID + minl]), ...);
}

template <size_t... Rs>
__device__ __forceinline__ void zero_bad_w(float (&w)[RACC], int n0w, int lane,
                                           int N, std::index_sequence<Rs...>) {
    ((w[Rs] = ((unsigned)(n0w + (int)Rs - CEN + lane) < (unsigned)N)
                  ? w[Rs] : 0.0f),
     ...);
}

template <int J, size_t... Rs>
__device__ __forceinline__ void consume_j(f32x4 (&acc)[RACC],
                                          const float (&w)[RACC], f32x4 xv,
                                          std::index_sequence<Rs...>) {
    (([&] {
         constexpr int r = (int)Rs;
         if constexpr (J - r >= 0 && J - r < WID) {
             const float ws = rdlane(w[r], J - r);
             acc[r].x = fmaf(xv.x, ws, acc[r].x);
             acc[r].y = fmaf(xv.y, ws, acc[r].y);
             acc[r].z = fmaf(xv.z, ws, acc[r].z);
             acc[r].w = fmaf(xv.w, ws, acc[r].w);
         }
     }()),
     ...);
}

// read row (16m + 4wv - 16 + Js) -> slot (16m + 4wv + Js) & 63
template <size_t... Js>
__device__ __forceinline__ void stream_rows(f32x4 (&acc)[RACC],
                                            const float (&w)[RACC],
                                            const float* xs, int sbase,
                                            int lane4,
                                            std::index_sequence<Js...>) {
    (([&] {
         const int s = (sbase + (int)Js) & (RING - 1);
         const f32x4 xv = ld4(xs + s * D_DIM + lane4);
         consume_j<(int)Js>(acc, w, xv, std::make_index_sequence<RACC>{});
     }()),
     ...);
}

template <size_t... Rs>
__device__ __forceinline__ void store_all(const f32x4 (&acc)[RACC], float szv,
                                          float* __restrict__ ob,
                                          std::index_sequence<Rs...>) {
    (([&] {
         constexpr int r = (int)Rs;
         const float inv = __builtin_amdgcn_rcpf(fmaxf(rdlane(szv, r), 1e-6f));
         f32x4 o;
         o.x = acc[r].x * inv; o.y = acc[r].y * inv;
         o.z = acc[r].z * inv; o.w = acc[r].w * inv;
         __builtin_nontemporal_store(o, (f32x4*)(ob + (size_t)r * D_DIM));
     }()),
     ...);
}

__device__ __forceinline__ void iter_body(
    float* xs, const float* __restrict__ xlane, const float* __restrict__ smb,
    const float* __restrict__ szb, float* __restrict__ obl, int n0, int m,
    int N, int wv, int lane, int lane4, float (&wcur)[RACC],
    float (&wnxt)[RACC], float& szcur, float& sznxt, int minl) {
    // phase 1: issue next-tile DMA first (vmcnt accounting relies on order)
    if (m < NI - 1)
        stage_iter(xs, xlane, n0 - CEN, m, N, wv);
    __builtin_amdgcn_sched_barrier(0);
    const int n1 = n0 + RITER * (m + 1) + wv * RACC;
    load_w(wnxt, smb, n1, minl, N, std::make_index_sequence<RACC>{});
    sznxt = szb[clampN(n1 + (lane & 3), N)];
    __builtin_amdgcn_sched_barrier(0);

    // phase 2: compute current 16 rows (4 per wave) from the ring
    const int n0w = n0 + RITER * m + wv * RACC;
    if (n0w < CEN || n0w + RACC - 1 + CEN >= N)      // boundary iters only
        zero_bad_w(wcur, n0w, lane, N, std::make_index_sequence<RACC>{});

    f32x4 acc[RACC] = {};
    stream_rows(acc, wcur, xs, RITER * m + wv * RACC, lane4,
                std::make_index_sequence<XROWS>{});
    store_all(acc, szcur, obl + (size_t)n0w * D_DIM,
              std::make_index_sequence<RACC>{});

    // counted barrier: wait only for this iter's 4 DMAs (4 w + 1 sz loads
    // + 4 NT stores are younger = 9); NT stores stay in flight to HBM.
    __builtin_amdgcn_sched_barrier(0);
    asm volatile("s_waitcnt vmcnt(9)" ::: "memory");
    __builtin_amdgcn_s_barrier();
    __builtin_amdgcn_sched_barrier(0);
}

__global__ __launch_bounds__(256) void local_enc_kernel(
    const float* __restrict__ x, const float* __restrict__ sizev,
    const float* __restrict__ sm, float* __restrict__ out, int N) {
    __shared__ float xs[RING * D_DIM];     // 64 rows x 1KB = 64 KB

    // XCD swizzle: XCD k owns batch k, strips consecutive -> L2-local
    const int bid   = blockIdx.x;
    const int swz   = (bid & 7) * 64 + (bid >> 3);
    const int strip = swz & 63;
    const int b     = swz >> 6;
    const int n0    = strip * CHUNK;
    const int tid   = threadIdx.x;
    const int wv    = tid >> 6;            // 0..3 -> row-group
    const int lane  = tid & 63;
    const int lane4 = lane * 4;            // this thread's 4 columns

    const size_t bN = (size_t)b * (size_t)N;
    const float* __restrict__ xlane = x + bN * D_DIM + lane4;
    const float* __restrict__ smb   = sm + bN * WID;
    const float* __restrict__ szb   = sizev + bN;
    float* __restrict__ obl         = out + bN * D_DIM + lane4;

    // prologue: stage first 48 rows + load iter-0 weights/sizes
    stage_prol(xs, xlane, n0 - CEN, N, wv, std::make_index_sequence<PROL / 4>{});
    const int minl = (lane < WID) ? lane : (WID - 1);
    float wA[RACC], wB[RACC];
    float szA, szB;
    load_w(wA, smb, n0 + wv * RACC, minl, N, std::make_index_sequence<RACC>{});
    szA = szb[clampN(n0 + wv * RACC + (lane & 3), N)];
    __syncthreads();                       // one-time full drain is fine

#pragma unroll 1
    for (int mp = 0; mp < NI / 2; ++mp) {
        const int m0 = 2 * mp;
        iter_body(xs, xlane, smb, szb, obl, n0, m0, N, wv, lane, lane4,
                  wA, wB, szA, szB, minl);
        iter_body(xs, xlane, smb, szb, obl, n0, m0 + 1, N, wv, lane, lane4,
                  wB, wA, szB, szA, minl);
    }
}

extern "C" void kernel_launch(void* const* d_in, const int* in_sizes, int n_in,
                              void* d_out, int out_size, void* d_ws, size_t ws_size,
                              hipStream_t stream) {
    const float* x  = (const float*)d_in[0];
    const float* sz = (const float*)d_in[1];
    const float* sm = (const float*)d_in[2];
    float* out = (float*)d_out;

    const int B = 8;
    const int N = 16384;

    dim3 grid((N / CHUNK) * B, 1, 1);   // 64 x 8 = 512 blocks, XCD-swizzled
    dim3 block(256, 1, 1);
    local_enc_kernel<<<grid, block, 0, stream>>>(x, sz, sm, out, N);
}